// Round 2
// baseline (1331.045 us; speedup 1.0000x reference)
//
#include <hip/hip_runtime.h>
#include <math.h>

#define D 1024
#define LSEQ 256
#define NB 128
#define GRID 512
#define TPB 256
constexpr float SCALE = 0.03125f; // 1/sqrt(1024)

// ---- grid-wide barrier: counter per barrier index, zeroed by host memset ----
__device__ __forceinline__ void grid_barrier(unsigned* bar, int idx) {
  __threadfence();
  __syncthreads();
  if (threadIdx.x == 0) {
    unsigned* c = bar + idx;
    __hip_atomic_fetch_add(c, 1u, __ATOMIC_ACQ_REL, __HIP_MEMORY_SCOPE_AGENT);
    while (__hip_atomic_load(c, __ATOMIC_ACQUIRE, __HIP_MEMORY_SCOPE_AGENT) < (unsigned)GRID) {
      __builtin_amdgcn_s_sleep(1);
    }
  }
  __syncthreads();
  __threadfence();
}

// ---- C[m,n] += A[m, kslice] * W ; M=128, N=1024, K=1024 split 8 ways over kb ----
// FORM 0: Wmat = W[n,k] ; FORM 1: Wmat = W[k,n]
// BIASMODE 0: none, 1: +bias[n], 2: +rowScale[m]*bias[n] (kb==0 only). C pre-zeroed.
template<int FORM, int BIASMODE>
__device__ __forceinline__ void gemm_stage(
    const float* __restrict__ A, size_t lda,
    const float* __restrict__ W,
    const float* __restrict__ bias,
    const float* __restrict__ rowScale,
    float* __restrict__ C,
    float* __restrict__ As, float* __restrict__ Ws,
    int bid, int tid) {
  const int nb = bid & 63, kb = bid >> 6;
  const int nbase = nb * 16;
  const int tm = tid & 31;   // m-quad
  const int tn = tid >> 5;   // n-pair
  float acc[4][2] = {{0.f,0.f},{0.f,0.f},{0.f,0.f},{0.f,0.f}};
  for (int it = 0; it < 4; ++it) {
    const int kc = kb * 128 + it * 32;
    __syncthreads();
    #pragma unroll
    for (int i = 0; i < 4; ++i) {
      int f = tid + i * 256;            // float4 id
      int m = f >> 3, kq = f & 7;
      float4 v = *(const float4*)(A + (size_t)m * lda + kc + kq * 4);
      As[(kq*4+0)*132 + m] = v.x; As[(kq*4+1)*132 + m] = v.y;
      As[(kq*4+2)*132 + m] = v.z; As[(kq*4+3)*132 + m] = v.w;
    }
    if (tid < 128) {
      if (FORM == 0) {
        int n = tid >> 3, kq = tid & 7;
        float4 v = *(const float4*)(W + (size_t)(nbase + n) * D + kc + kq * 4);
        Ws[(kq*4+0)*20 + n] = v.x; Ws[(kq*4+1)*20 + n] = v.y;
        Ws[(kq*4+2)*20 + n] = v.z; Ws[(kq*4+3)*20 + n] = v.w;
      } else {
        int kk = tid >> 2, nq = tid & 3;
        float4 v = *(const float4*)(W + (size_t)(kc + kk) * D + nbase + nq * 4);
        *(float4*)&Ws[kk*20 + nq*4] = v;
      }
    }
    __syncthreads();
    #pragma unroll
    for (int kk = 0; kk < 32; ++kk) {
      float4 a4 = *(const float4*)&As[kk*132 + tm*4];
      float2 w2 = *(const float2*)&Ws[kk*20 + tn*2];
      acc[0][0] = fmaf(a4.x, w2.x, acc[0][0]); acc[0][1] = fmaf(a4.x, w2.y, acc[0][1]);
      acc[1][0] = fmaf(a4.y, w2.x, acc[1][0]); acc[1][1] = fmaf(a4.y, w2.y, acc[1][1]);
      acc[2][0] = fmaf(a4.z, w2.x, acc[2][0]); acc[2][1] = fmaf(a4.z, w2.y, acc[2][1]);
      acc[3][0] = fmaf(a4.w, w2.x, acc[3][0]); acc[3][1] = fmaf(a4.w, w2.y, acc[3][1]);
    }
  }
  #pragma unroll
  for (int i = 0; i < 4; ++i) {
    int m = tm * 4 + i;
    #pragma unroll
    for (int j = 0; j < 2; ++j) {
      int n = nbase + tn * 2 + j;
      float v = acc[i][j];
      if (kb == 0) {
        if (BIASMODE == 1) v += bias[n];
        else if (BIASMODE == 2) v += rowScale[m] * bias[n];
      }
      atomicAdd(&C[(size_t)m * D + n], v);
    }
  }
}

// ---- out = (merged m) @ v_w^T + v_b, merge of 4 accP chunks fused into A-staging ----
__device__ __forceinline__ void merge_gemm(
    const float* __restrict__ accP, const float* __restrict__ MP,
    const float* __restrict__ ZP,
    const float* __restrict__ W, const float* __restrict__ bias,
    float* __restrict__ C,
    float* __restrict__ As, float* __restrict__ Ws, float* __restrict__ esh,
    int bid, int tid) {
  const int nb = bid & 63, kb = bid >> 6;
  const int nbase = nb * 16;
  const int tm = tid & 31, tn = tid >> 5;
  if (tid < 128) {
    int b = tid;
    float M0 = MP[b], M1 = MP[128+b], M2 = MP[256+b], M3 = MP[384+b];
    float Mg = fmaxf(fmaxf(M0, M1), fmaxf(M2, M3));
    float e0 = expf(M0-Mg), e1 = expf(M1-Mg), e2 = expf(M2-Mg), e3 = expf(M3-Mg);
    float Zg = e0*ZP[b] + e1*ZP[128+b] + e2*ZP[256+b] + e3*ZP[384+b];
    float inv = 1.f / Zg;
    esh[b] = e0*inv; esh[128+b] = e1*inv; esh[256+b] = e2*inv; esh[384+b] = e3*inv;
  }
  float acc[4][2] = {{0.f,0.f},{0.f,0.f},{0.f,0.f},{0.f,0.f}};
  for (int it = 0; it < 4; ++it) {
    const int kc = kb * 128 + it * 32;
    __syncthreads();
    #pragma unroll
    for (int i = 0; i < 4; ++i) {
      int f = tid + i * 256;
      int m = f >> 3, kq = f & 7;
      const float* base = accP + (size_t)m * D + kc + kq * 4;
      float4 v0 = *(const float4*)(base);
      float4 v1 = *(const float4*)(base + (size_t)NB*D);
      float4 v2 = *(const float4*)(base + (size_t)2*NB*D);
      float4 v3 = *(const float4*)(base + (size_t)3*NB*D);
      float e0 = esh[m], e1 = esh[128+m], e2 = esh[256+m], e3 = esh[384+m];
      float4 v;
      v.x = e0*v0.x + e1*v1.x + e2*v2.x + e3*v3.x;
      v.y = e0*v0.y + e1*v1.y + e2*v2.y + e3*v3.y;
      v.z = e0*v0.z + e1*v1.z + e2*v2.z + e3*v3.z;
      v.w = e0*v0.w + e1*v1.w + e2*v2.w + e3*v3.w;
      As[(kq*4+0)*132 + m] = v.x; As[(kq*4+1)*132 + m] = v.y;
      As[(kq*4+2)*132 + m] = v.z; As[(kq*4+3)*132 + m] = v.w;
    }
    if (tid < 128) {
      int n = tid >> 3, kq = tid & 7;
      float4 v = *(const float4*)(W + (size_t)(nbase + n) * D + kc + kq * 4);
      Ws[(kq*4+0)*20 + n] = v.x; Ws[(kq*4+1)*20 + n] = v.y;
      Ws[(kq*4+2)*20 + n] = v.z; Ws[(kq*4+3)*20 + n] = v.w;
    }
    __syncthreads();
    #pragma unroll
    for (int kk = 0; kk < 32; ++kk) {
      float4 a4 = *(const float4*)&As[kk*132 + tm*4];
      float2 w2 = *(const float2*)&Ws[kk*20 + tn*2];
      acc[0][0] = fmaf(a4.x, w2.x, acc[0][0]); acc[0][1] = fmaf(a4.x, w2.y, acc[0][1]);
      acc[1][0] = fmaf(a4.y, w2.x, acc[1][0]); acc[1][1] = fmaf(a4.y, w2.y, acc[1][1]);
      acc[2][0] = fmaf(a4.z, w2.x, acc[2][0]); acc[2][1] = fmaf(a4.z, w2.y, acc[2][1]);
      acc[3][0] = fmaf(a4.w, w2.x, acc[3][0]); acc[3][1] = fmaf(a4.w, w2.y, acc[3][1]);
    }
  }
  #pragma unroll
  for (int i = 0; i < 4; ++i) {
    int m = tm * 4 + i;
    #pragma unroll
    for (int j = 0; j < 2; ++j) {
      int n = nbase + tn * 2 + j;
      float v = acc[i][j];
      if (kb == 0) v += bias[n];
      atomicAdd(&C[(size_t)m * D + n], v);
    }
  }
}

// ---- caption stream: attA0 weights + weighted row accumulation ----
__device__ __forceinline__ void cap_stage(
    const float* __restrict__ cap, const float* __restrict__ p,
    const float* __restrict__ qdot, float* __restrict__ nacc,
    float* __restrict__ sA, float* __restrict__ smemf, int bid, int tid) {
  const int b = bid >> 2, chunk = bid & 3;
  const int wid = tid >> 6, lane = tid & 63;
  float* nsh = smemf;            // 4096 floats
  float* sAsh = smemf + 4096;    // 4
  float4 p4[4], acc[4];
  const float* pb = p + (size_t)b * D;
  #pragma unroll
  for (int s = 0; s < 4; ++s) {
    p4[s] = *(const float4*)(pb + s * 256 + lane * 4);
    acc[s] = make_float4(0.f, 0.f, 0.f, 0.f);
  }
  const float qd = qdot[b];
  float sAw = 0.f;
  const float* capb = cap + (size_t)b * LSEQ * D;
  const int r0 = chunk * 64 + wid;
  float4 r4[4], r4n[4];
  {
    const float* row = capb + (size_t)r0 * D;
    #pragma unroll
    for (int s = 0; s < 4; ++s) r4[s] = *(const float4*)(row + s * 256 + lane * 4);
  }
  for (int i = 0; i < 16; ++i) {
    if (i < 15) {
      const float* row = capb + (size_t)(r0 + (i + 1) * 4) * D;
      #pragma unroll
      for (int s = 0; s < 4; ++s) r4n[s] = *(const float4*)(row + s * 256 + lane * 4);
    }
    float t = 0.f;
    #pragma unroll
    for (int s = 0; s < 4; ++s) {
      t = fmaf(p4[s].x, r4[s].x, t); t = fmaf(p4[s].y, r4[s].y, t);
      t = fmaf(p4[s].z, r4[s].z, t); t = fmaf(p4[s].w, r4[s].w, t);
    }
    #pragma unroll
    for (int off = 32; off; off >>= 1) t += __shfl_xor(t, off);
    float a = SCALE * (t + qd);
    sAw += a;
    #pragma unroll
    for (int s = 0; s < 4; ++s) {
      acc[s].x = fmaf(a, r4[s].x, acc[s].x); acc[s].y = fmaf(a, r4[s].y, acc[s].y);
      acc[s].z = fmaf(a, r4[s].z, acc[s].z); acc[s].w = fmaf(a, r4[s].w, acc[s].w);
    }
    #pragma unroll
    for (int s = 0; s < 4; ++s) r4[s] = r4n[s];
  }
  #pragma unroll
  for (int s = 0; s < 4; ++s) *(float4*)&nsh[wid*D + s*256 + lane*4] = acc[s];
  if (lane == 0) sAsh[wid] = sAw;
  __syncthreads();
  float4 v = make_float4(0.f, 0.f, 0.f, 0.f);
  #pragma unroll
  for (int w = 0; w < 4; ++w) {
    float4 x = *(const float4*)&nsh[w*D + tid*4];
    v.x += x.x; v.y += x.y; v.z += x.z; v.w += x.w;
  }
  float* nb = nacc + (size_t)b * D + tid * 4;
  atomicAdd(nb + 0, v.x); atomicAdd(nb + 1, v.y);
  atomicAdd(nb + 2, v.z); atomicAdd(nb + 3, v.w);
  if (tid == 0) atomicAdd(&sA[b], sAsh[0] + sAsh[1] + sAsh[2] + sAsh[3]);
}

// ---- target stream: online softmax partials per chunk ----
__device__ __forceinline__ void tar_stage(
    const float* __restrict__ tar, const float* __restrict__ wv,
    const float* __restrict__ cbp, float* __restrict__ accP,
    float* __restrict__ MP, float* __restrict__ ZP,
    float* __restrict__ smemf, int bid, int tid) {
  const int b = bid >> 2, chunk = bid & 3;
  const int wid = tid >> 6, lane = tid & 63;
  float* ash = smemf;
  float* msh = smemf + 4096;
  float* zsh = smemf + 4100;
  float4 w4[4], acc[4];
  const float* wb = wv + (size_t)b * D;
  #pragma unroll
  for (int s = 0; s < 4; ++s) {
    w4[s] = *(const float4*)(wb + s * 256 + lane * 4);
    acc[s] = make_float4(0.f, 0.f, 0.f, 0.f);
  }
  const float cbb = cbp[b];
  float M = -INFINITY, Z = 0.f;
  const float* tb = tar + (size_t)b * LSEQ * D;
  const int r0 = chunk * 64 + wid;
  float4 r4[4], r4n[4];
  {
    const float* row = tb + (size_t)r0 * D;
    #pragma unroll
    for (int s = 0; s < 4; ++s) r4[s] = *(const float4*)(row + s * 256 + lane * 4);
  }
  for (int i = 0; i < 16; ++i) {
    if (i < 15) {
      const float* row = tb + (size_t)(r0 + (i + 1) * 4) * D;
      #pragma unroll
      for (int s = 0; s < 4; ++s) r4n[s] = *(const float4*)(row + s * 256 + lane * 4);
    }
    float sc = 0.f;
    #pragma unroll
    for (int s = 0; s < 4; ++s) {
      sc = fmaf(w4[s].x, r4[s].x, sc); sc = fmaf(w4[s].y, r4[s].y, sc);
      sc = fmaf(w4[s].z, r4[s].z, sc); sc = fmaf(w4[s].w, r4[s].w, sc);
    }
    #pragma unroll
    for (int off = 32; off; off >>= 1) sc += __shfl_xor(sc, off);
    float st = SCALE * (sc + cbb);
    if (st <= M) {            // wave-uniform branch
      float e = expf(st - M);
      Z += e;
      #pragma unroll
      for (int s = 0; s < 4; ++s) {
        acc[s].x = fmaf(e, r4[s].x, acc[s].x); acc[s].y = fmaf(e, r4[s].y, acc[s].y);
        acc[s].z = fmaf(e, r4[s].z, acc[s].z); acc[s].w = fmaf(e, r4[s].w, acc[s].w);
      }
    } else {
      float r = expf(M - st); // first iter: exp(-inf)=0
      Z = fmaf(Z, r, 1.f);
      #pragma unroll
      for (int s = 0; s < 4; ++s) {
        acc[s].x = fmaf(acc[s].x, r, r4[s].x); acc[s].y = fmaf(acc[s].y, r, r4[s].y);
        acc[s].z = fmaf(acc[s].z, r, r4[s].z); acc[s].w = fmaf(acc[s].w, r, r4[s].w);
      }
      M = st;
    }
    #pragma unroll
    for (int s = 0; s < 4; ++s) r4[s] = r4n[s];
  }
  #pragma unroll
  for (int s = 0; s < 4; ++s) *(float4*)&ash[wid*D + s*256 + lane*4] = acc[s];
  if (lane == 0) { msh[wid] = M; zsh[wid] = Z; }
  __syncthreads();
  float Mb = fmaxf(fmaxf(msh[0], msh[1]), fmaxf(msh[2], msh[3]));
  float e0 = expf(msh[0]-Mb), e1 = expf(msh[1]-Mb);
  float e2 = expf(msh[2]-Mb), e3 = expf(msh[3]-Mb);
  float4 x0 = *(const float4*)&ash[0*D + tid*4];
  float4 x1 = *(const float4*)&ash[1*D + tid*4];
  float4 x2 = *(const float4*)&ash[2*D + tid*4];
  float4 x3 = *(const float4*)&ash[3*D + tid*4];
  float4 v;
  v.x = e0*x0.x + e1*x1.x + e2*x2.x + e3*x3.x;
  v.y = e0*x0.y + e1*x1.y + e2*x2.y + e3*x3.y;
  v.z = e0*x0.z + e1*x1.z + e2*x2.z + e3*x3.z;
  v.w = e0*x0.w + e1*x1.w + e2*x2.w + e3*x3.w;
  *(float4*)(accP + ((size_t)chunk * NB + b) * D + tid * 4) = v;
  if (tid == 0) {
    MP[chunk * NB + b] = Mb;
    ZP[chunk * NB + b] = e0*zsh[0] + e1*zsh[1] + e2*zsh[2] + e3*zsh[3];
  }
}

__global__ __launch_bounds__(TPB, 2) void fused_hinge_kernel(
    const float* __restrict__ ref, const float* __restrict__ cap,
    const float* __restrict__ tar,
    const float* __restrict__ qr_w, const float* __restrict__ qr_b,
    const float* __restrict__ ktxt_w, const float* __restrict__ ktxt_b,
    const float* __restrict__ ktar_w, const float* __restrict__ ktar_b,
    const float* __restrict__ v_w, const float* __restrict__ v_b,
    float* __restrict__ out, float* __restrict__ ws) {
  __shared__ float smemf[5376];   // gemm: As 4224 + Ws 640 + esh 512 ; streams: 4096+8
  unsigned* bar = (unsigned*)ws;  // 32 counters, zeroed by host memset
  float* q0   = ws + 32;
  float* p    = ws + 131104;
  float* u    = ws + 262176;
  float* w    = ws + 393248;
  float* nacc = ws + 524320;
  float* qdot = ws + 655392;
  float* cb   = ws + 655520;
  float* sA   = ws + 655648;
  float* MP   = ws + 655776;
  float* ZP   = ws + 656288;
  float* accP = ws + 656800;
  const int bid = blockIdx.x, tid = threadIdx.x;
  const int gtid = bid * TPB + tid;

  // stage 0: zero all atomic accumulators + out
  float4 z4 = make_float4(0.f, 0.f, 0.f, 0.f);
  float4* zr = (float4*)(ws + 32);
  for (int i = gtid; i < 163936; i += GRID * TPB) zr[i] = z4;
  float4* oz = (float4*)out;
  if (gtid < 32768) oz[gtid] = z4;
  grid_barrier(bar, 0);

  // A: q0 = ref[:,0,:] @ qr_w^T + qr_b
  gemm_stage<0,1>(ref, (size_t)LSEQ * D, qr_w, qr_b, nullptr, q0,
                  smemf, smemf + 4224, bid, tid);
  grid_barrier(bar, 1);

  // B: p = q0 @ ktxt_w ; qdot[b] = q0[b].ktxt_b
  gemm_stage<1,0>(q0, D, ktxt_w, nullptr, nullptr, p,
                  smemf, smemf + 4224, bid, tid);
  if ((bid & 63) == 0) {
    int kb = bid >> 6;
    int m = tid >> 1, kh = tid & 1;
    const float* qrow = q0 + (size_t)m * D + kb * 128 + kh * 64;
    const float* bb = ktxt_b + kb * 128 + kh * 64;
    float s = 0.f;
    #pragma unroll
    for (int j = 0; j < 64; j += 4) {
      float4 a = *(const float4*)(qrow + j);
      float4 c = *(const float4*)(bb + j);
      s = fmaf(a.x, c.x, s); s = fmaf(a.y, c.y, s);
      s = fmaf(a.z, c.z, s); s = fmaf(a.w, c.w, s);
    }
    s += __shfl_xor(s, 1);
    if (kh == 0) atomicAdd(&qdot[m], s);
  }
  grid_barrier(bar, 2);

  // C: stream caption -> nacc, sA
  cap_stage(cap, p, qdot, nacc, sA, smemf, bid, tid);
  grid_barrier(bar, 3);

  // D: u = nacc @ ktxt_w^T + sA*ktxt_b
  gemm_stage<0,2>(nacc, D, ktxt_w, ktxt_b, sA, u,
                  smemf, smemf + 4224, bid, tid);
  grid_barrier(bar, 4);

  // E: w = u @ ktar_w ; cb[b] = u[b].ktar_b
  gemm_stage<1,0>(u, D, ktar_w, nullptr, nullptr, w,
                  smemf, smemf + 4224, bid, tid);
  if ((bid & 63) == 0) {
    int kb = bid >> 6;
    int m = tid >> 1, kh = tid & 1;
    const float* urow = u + (size_t)m * D + kb * 128 + kh * 64;
    const float* bb = ktar_b + kb * 128 + kh * 64;
    float s = 0.f;
    #pragma unroll
    for (int j = 0; j < 64; j += 4) {
      float4 a = *(const float4*)(urow + j);
      float4 c = *(const float4*)(bb + j);
      s = fmaf(a.x, c.x, s); s = fmaf(a.y, c.y, s);
      s = fmaf(a.z, c.z, s); s = fmaf(a.w, c.w, s);
    }
    s += __shfl_xor(s, 1);
    if (kh == 0) atomicAdd(&cb[m], s);
  }
  grid_barrier(bar, 5);

  // F: stream target with online softmax -> accP/MP/ZP partials
  tar_stage(tar, w, cb, accP, MP, ZP, smemf, bid, tid);
  grid_barrier(bar, 6);

  // G: out = merge(accP) @ v_w^T + v_b
  merge_gemm(accP, MP, ZP, v_w, v_b, out,
             smemf, smemf + 4224, smemf + 4864, bid, tid);
}

extern "C" void kernel_launch(void* const* d_in, const int* in_sizes, int n_in,
                              void* d_out, int out_size, void* d_ws, size_t ws_size,
                              hipStream_t stream) {
  const float* ref    = (const float*)d_in[0];
  const float* cap    = (const float*)d_in[1];
  const float* tar    = (const float*)d_in[2];
  const float* qr_w   = (const float*)d_in[3];
  const float* qr_b   = (const float*)d_in[4];
  const float* ktxt_w = (const float*)d_in[5];
  const float* ktxt_b = (const float*)d_in[6];
  const float* ktar_w = (const float*)d_in[7];
  const float* ktar_b = (const float*)d_in[8];
  const float* v_w    = (const float*)d_in[9];
  const float* v_b    = (const float*)d_in[10];
  float* out = (float*)d_out;
  float* ws  = (float*)d_ws;

  // zero only the 32 barrier counters; kernel zeroes everything else in stage 0
  hipMemsetAsync(ws, 0, 32 * sizeof(unsigned), stream);
  fused_hinge_kernel<<<GRID, TPB, 0, stream>>>(
      ref, cap, tar, qr_w, qr_b, ktxt_w, ktxt_b, ktar_w, ktar_b, v_w, v_b,
      out, ws);
}

// Round 3
// 430.458 us; speedup vs baseline: 3.0922x; 3.0922x over previous
//
#include <hip/hip_runtime.h>
#include <math.h>

#define D 1024
#define LSEQ 256
#define NB 128
constexpr float SCALE = 0.03125f; // 1/sqrt(1024)

// ---------------- GEMM with k-split partials, no atomics ----------------
// C = A @ W(FORM); M=128, N=1024, K=1024. grid dim3(32,8): x=nb (32 cols), y=kb (128 k).
// Block: 128m x 32n over 4 iters of 32k. Threads 256: tm=tid&31 (4 m), tn=tid>>5 (4 n).
// Writes Cpart[kb][128][1024] (plain stores; consumer sums the 8 partials).
// FORM 0: C[m,n]=sum_k A[m,k]*W[n,k] ; FORM 1: C[m,n]=sum_k A[m,k]*W[k,n]
// SRCN: A itself is the sum of SRCN partials (stride srcStride).
// BIASMODE (kb==0 only): 0 none; 1 +bias[n]; 2 +rowSum(sAP)[m]*bias[n]
// SCALEA: A rows scaled by 1/(sum of 4 ZP partials) during staging (softmax merge).
template<int FORM, int SRCN, int BIASMODE, int SCALEA>
__global__ __launch_bounds__(256) void gemm_kernel(
    const float* __restrict__ A, size_t lda, size_t srcStride,
    const float* __restrict__ W,
    const float* __restrict__ bias,
    const float* __restrict__ sAP,   // [4][128] partial row sums (BIASMODE 2)
    const float* __restrict__ ZP,    // [4][128] partial Z (SCALEA)
    float* __restrict__ Cpart) {
  __shared__ float As[32 * 132];
  __shared__ float Ws[32 * 36];
  __shared__ float rowf[128];
  const int nbase = blockIdx.x * 32;
  const int kb = blockIdx.y;
  const int tid = threadIdx.x;
  const int tm = tid & 31, tn = tid >> 5;

  if ((SCALEA || BIASMODE == 2) && tid < 128) {
    if (SCALEA) {
      float z = ZP[tid] + ZP[128 + tid] + ZP[256 + tid] + ZP[384 + tid];
      rowf[tid] = 1.f / z;
    } else {
      rowf[tid] = sAP[tid] + sAP[128 + tid] + sAP[256 + tid] + sAP[384 + tid];
    }
  }

  float acc[4][4] = {{0.f}};
  for (int it = 0; it < 4; ++it) {
    const int kc = kb * 128 + it * 32;
    __syncthreads();
    // stage A chunk: 128m x 32k (sum SRCN partials, optional row scale)
    #pragma unroll
    for (int i = 0; i < 4; ++i) {
      int f = tid + i * 256;           // 0..1023 float4 ids
      int m = f >> 3, kq = f & 7;
      const float* src = A + (size_t)m * lda + kc + kq * 4;
      float4 v = *(const float4*)(src);
      #pragma unroll
      for (int s = 1; s < SRCN; ++s) {
        float4 t = *(const float4*)(src + (size_t)s * srcStride);
        v.x += t.x; v.y += t.y; v.z += t.z; v.w += t.w;
      }
      if (SCALEA) { float sc = rowf[m]; v.x *= sc; v.y *= sc; v.z *= sc; v.w *= sc; }
      As[(kq*4+0)*132 + m] = v.x; As[(kq*4+1)*132 + m] = v.y;
      As[(kq*4+2)*132 + m] = v.z; As[(kq*4+3)*132 + m] = v.w;
    }
    // stage W chunk: 32k x 32n
    if (FORM == 1) {
      int kk = tid >> 3, nq = tid & 7;
      float4 v = *(const float4*)(W + (size_t)(kc + kk) * D + nbase + nq * 4);
      *(float4*)&Ws[kk*36 + nq*4] = v;
    } else {
      int n = tid >> 3, kq = tid & 7;
      float4 v = *(const float4*)(W + (size_t)(nbase + n) * D + kc + kq * 4);
      Ws[(kq*4+0)*36 + n] = v.x; Ws[(kq*4+1)*36 + n] = v.y;
      Ws[(kq*4+2)*36 + n] = v.z; Ws[(kq*4+3)*36 + n] = v.w;
    }
    __syncthreads();
    #pragma unroll
    for (int kk = 0; kk < 32; ++kk) {
      float4 a4 = *(const float4*)&As[kk*132 + tm*4];
      float4 w4 = *(const float4*)&Ws[kk*36 + tn*4];
      float av[4] = {a4.x, a4.y, a4.z, a4.w};
      float wv[4] = {w4.x, w4.y, w4.z, w4.w};
      #pragma unroll
      for (int i = 0; i < 4; ++i)
        #pragma unroll
        for (int j = 0; j < 4; ++j)
          acc[i][j] = fmaf(av[i], wv[j], acc[i][j]);
    }
  }
  float* Cout = Cpart + (size_t)kb * (NB * D);
  #pragma unroll
  for (int i = 0; i < 4; ++i) {
    int m = tm * 4 + i;
    int n = nbase + tn * 4;
    float4 st = make_float4(acc[i][0], acc[i][1], acc[i][2], acc[i][3]);
    if (kb == 0) {
      if (BIASMODE == 1) {
        st.x += bias[n]; st.y += bias[n+1]; st.z += bias[n+2]; st.w += bias[n+3];
      } else if (BIASMODE == 2) {
        float rs = rowf[m];
        st.x = fmaf(rs, bias[n],   st.x); st.y = fmaf(rs, bias[n+1], st.y);
        st.z = fmaf(rs, bias[n+2], st.z); st.w = fmaf(rs, bias[n+3], st.w);
      }
    }
    *(float4*)(Cout + (size_t)m * D + n) = st;
  }
}

// ---------------- caption stream ----------------
// block (chunk,b): attA0[c] = SCALE*(p[b].cap[b,c] + qdot[b]) for its 64 c's;
// writes naccP[chunk][b][:] = sum_c attA0*cap[b,c,:], sAP[chunk][b] = sum_c attA0.
// p = sum of 8 ppart; qdot computed per-wave from sum of 8 q0part . ktxt_b.
__global__ __launch_bounds__(256) void cap_kernel(
    const float* __restrict__ cap,
    const float* __restrict__ ppart,
    const float* __restrict__ q0part,
    const float* __restrict__ ktxt_b,
    float* __restrict__ naccP,
    float* __restrict__ sAP) {
  const int chunk = blockIdx.x, b = blockIdx.y;
  const int wid = threadIdx.x >> 6, lane = threadIdx.x & 63;
  __shared__ float nsh[4 * D];
  __shared__ float ssh[4];
  float4 p4[4], acc[4];
  float qloc = 0.f;
  #pragma unroll
  for (int s = 0; s < 4; ++s) {
    int d = s * 256 + lane * 4;
    const float* pb = ppart + (size_t)b * D + d;
    const float* qb = q0part + (size_t)b * D + d;
    float4 pv = *(const float4*)pb;
    float4 qv = *(const float4*)qb;
    #pragma unroll
    for (int t = 1; t < 8; ++t) {
      float4 x = *(const float4*)(pb + (size_t)t * (NB * D));
      float4 y = *(const float4*)(qb + (size_t)t * (NB * D));
      pv.x += x.x; pv.y += x.y; pv.z += x.z; pv.w += x.w;
      qv.x += y.x; qv.y += y.y; qv.z += y.z; qv.w += y.w;
    }
    p4[s] = pv;
    acc[s] = make_float4(0.f, 0.f, 0.f, 0.f);
    float4 kb4 = *(const float4*)(ktxt_b + d);
    qloc = fmaf(qv.x, kb4.x, qloc); qloc = fmaf(qv.y, kb4.y, qloc);
    qloc = fmaf(qv.z, kb4.z, qloc); qloc = fmaf(qv.w, kb4.w, qloc);
  }
  #pragma unroll
  for (int off = 32; off; off >>= 1) qloc += __shfl_xor(qloc, off);
  const float qd = qloc;   // each wave covers all 1024 d's -> full dot

  float sAw = 0.f;
  const float* capb = cap + (size_t)b * LSEQ * D;
  const int r0 = chunk * 64 + wid;
  float4 r4[4], r4n[4];
  {
    const float* row = capb + (size_t)r0 * D;
    #pragma unroll
    for (int s = 0; s < 4; ++s) r4[s] = *(const float4*)(row + s * 256 + lane * 4);
  }
  for (int i = 0; i < 16; ++i) {
    if (i < 15) {
      const float* row = capb + (size_t)(r0 + (i + 1) * 4) * D;
      #pragma unroll
      for (int s = 0; s < 4; ++s) r4n[s] = *(const float4*)(row + s * 256 + lane * 4);
    }
    float t = 0.f;
    #pragma unroll
    for (int s = 0; s < 4; ++s) {
      t = fmaf(p4[s].x, r4[s].x, t); t = fmaf(p4[s].y, r4[s].y, t);
      t = fmaf(p4[s].z, r4[s].z, t); t = fmaf(p4[s].w, r4[s].w, t);
    }
    #pragma unroll
    for (int off = 32; off; off >>= 1) t += __shfl_xor(t, off);
    float a = SCALE * (t + qd);
    sAw += a;
    #pragma unroll
    for (int s = 0; s < 4; ++s) {
      acc[s].x = fmaf(a, r4[s].x, acc[s].x); acc[s].y = fmaf(a, r4[s].y, acc[s].y);
      acc[s].z = fmaf(a, r4[s].z, acc[s].z); acc[s].w = fmaf(a, r4[s].w, acc[s].w);
    }
    #pragma unroll
    for (int s = 0; s < 4; ++s) r4[s] = r4n[s];
  }
  #pragma unroll
  for (int s = 0; s < 4; ++s) *(float4*)&nsh[wid * D + s * 256 + lane * 4] = acc[s];
  if (lane == 0) ssh[wid] = sAw;
  __syncthreads();
  const int tid = threadIdx.x;
  float4 v = make_float4(0.f, 0.f, 0.f, 0.f);
  #pragma unroll
  for (int w = 0; w < 4; ++w) {
    float4 x = *(const float4*)&nsh[w * D + tid * 4];
    v.x += x.x; v.y += x.y; v.z += x.z; v.w += x.w;
  }
  *(float4*)(naccP + ((size_t)chunk * NB + b) * D + tid * 4) = v;
  if (tid == 0) sAP[chunk * NB + b] = ssh[0] + ssh[1] + ssh[2] + ssh[3];
}

// ---------------- target stream (plain exp, no online max) ----------------
// block (chunk,b): st = SCALE*(w[b].tar[b,t] + cb[b]) for its 64 t's;
// writes accP[chunk][b][:] = sum_t exp(st)*tar[b,t,:], ZP[chunk][b] = sum_t exp(st).
__global__ __launch_bounds__(256) void tar_kernel(
    const float* __restrict__ tar,
    const float* __restrict__ wpart,
    const float* __restrict__ upart,
    const float* __restrict__ ktar_b,
    float* __restrict__ accP,
    float* __restrict__ ZP) {
  const int chunk = blockIdx.x, b = blockIdx.y;
  const int wid = threadIdx.x >> 6, lane = threadIdx.x & 63;
  __shared__ float ash[4 * D];
  __shared__ float zsh[4];
  float4 w4[4], acc[4];
  float cloc = 0.f;
  #pragma unroll
  for (int s = 0; s < 4; ++s) {
    int d = s * 256 + lane * 4;
    const float* wb = wpart + (size_t)b * D + d;
    const float* ub = upart + (size_t)b * D + d;
    float4 wv = *(const float4*)wb;
    float4 uv = *(const float4*)ub;
    #pragma unroll
    for (int t = 1; t < 8; ++t) {
      float4 x = *(const float4*)(wb + (size_t)t * (NB * D));
      float4 y = *(const float4*)(ub + (size_t)t * (NB * D));
      wv.x += x.x; wv.y += x.y; wv.z += x.z; wv.w += x.w;
      uv.x += y.x; uv.y += y.y; uv.z += y.z; uv.w += y.w;
    }
    w4[s] = wv;
    acc[s] = make_float4(0.f, 0.f, 0.f, 0.f);
    float4 kb4 = *(const float4*)(ktar_b + d);
    cloc = fmaf(uv.x, kb4.x, cloc); cloc = fmaf(uv.y, kb4.y, cloc);
    cloc = fmaf(uv.z, kb4.z, cloc); cloc = fmaf(uv.w, kb4.w, cloc);
  }
  #pragma unroll
  for (int off = 32; off; off >>= 1) cloc += __shfl_xor(cloc, off);
  const float cb = cloc;

  float Z = 0.f;
  const float* tb = tar + (size_t)b * LSEQ * D;
  const int r0 = chunk * 64 + wid;
  float4 r4[4], r4n[4];
  {
    const float* row = tb + (size_t)r0 * D;
    #pragma unroll
    for (int s = 0; s < 4; ++s) r4[s] = *(const float4*)(row + s * 256 + lane * 4);
  }
  for (int i = 0; i < 16; ++i) {
    if (i < 15) {
      const float* row = tb + (size_t)(r0 + (i + 1) * 4) * D;
      #pragma unroll
      for (int s = 0; s < 4; ++s) r4n[s] = *(const float4*)(row + s * 256 + lane * 4);
    }
    float sc = 0.f;
    #pragma unroll
    for (int s = 0; s < 4; ++s) {
      sc = fmaf(w4[s].x, r4[s].x, sc); sc = fmaf(w4[s].y, r4[s].y, sc);
      sc = fmaf(w4[s].z, r4[s].z, sc); sc = fmaf(w4[s].w, r4[s].w, sc);
    }
    #pragma unroll
    for (int off = 32; off; off >>= 1) sc += __shfl_xor(sc, off);
    float e = expf(SCALE * (sc + cb));
    Z += e;
    #pragma unroll
    for (int s = 0; s < 4; ++s) {
      acc[s].x = fmaf(e, r4[s].x, acc[s].x); acc[s].y = fmaf(e, r4[s].y, acc[s].y);
      acc[s].z = fmaf(e, r4[s].z, acc[s].z); acc[s].w = fmaf(e, r4[s].w, acc[s].w);
    }
    #pragma unroll
    for (int s = 0; s < 4; ++s) r4[s] = r4n[s];
  }
  #pragma unroll
  for (int s = 0; s < 4; ++s) *(float4*)&ash[wid * D + s * 256 + lane * 4] = acc[s];
  if (lane == 0) zsh[wid] = Z;
  __syncthreads();
  const int tid = threadIdx.x;
  float4 v = make_float4(0.f, 0.f, 0.f, 0.f);
  #pragma unroll
  for (int w = 0; w < 4; ++w) {
    float4 x = *(const float4*)&ash[w * D + tid * 4];
    v.x += x.x; v.y += x.y; v.z += x.z; v.w += x.w;
  }
  *(float4*)(accP + ((size_t)chunk * NB + b) * D + tid * 4) = v;
  if (tid == 0) ZP[chunk * NB + b] = zsh[0] + zsh[1] + zsh[2] + zsh[3];
}

// ---------------- final 8-partial reduce ----------------
__global__ __launch_bounds__(256) void reduce_out_kernel(
    const float* __restrict__ outPart, float* __restrict__ out) {
  int i = blockIdx.x * 256 + threadIdx.x;   // 32768 float4s
  const float4* src = (const float4*)outPart;
  float4 v = src[i];
  #pragma unroll
  for (int t = 1; t < 8; ++t) {
    float4 x = src[(size_t)t * 32768 + i];
    v.x += x.x; v.y += x.y; v.z += x.z; v.w += x.w;
  }
  ((float4*)out)[i] = v;
}

extern "C" void kernel_launch(void* const* d_in, const int* in_sizes, int n_in,
                              void* d_out, int out_size, void* d_ws, size_t ws_size,
                              hipStream_t stream) {
  const float* ref    = (const float*)d_in[0];
  const float* cap    = (const float*)d_in[1];
  const float* tar    = (const float*)d_in[2];
  const float* qr_w   = (const float*)d_in[3];
  const float* qr_b   = (const float*)d_in[4];
  const float* ktxt_w = (const float*)d_in[5];
  const float* ktxt_b = (const float*)d_in[6];
  const float* ktar_w = (const float*)d_in[7];
  const float* ktar_b = (const float*)d_in[8];
  const float* v_w    = (const float*)d_in[9];
  const float* v_b    = (const float*)d_in[10];
  float* out = (float*)d_out;
  float* ws  = (float*)d_ws;

  const size_t P = (size_t)NB * D;          // 131072
  float* q0part  = ws;                      // 8*P
  float* ppart   = ws + 8 * P;              // 8*P
  float* upart   = ws + 16 * P;             // 8*P
  float* wpart   = ws + 24 * P;             // 8*P
  float* naccP   = ws + 32 * P;             // 4*P
  float* accP    = ws + 36 * P;             // 4*P
  float* outPart = ws + 40 * P;             // 8*P
  float* sAP     = ws + 48 * P;             // 512
  float* ZP      = ws + 48 * P + 512;       // 512

  dim3 gG(32, 8), bG(256);
  // q0 = ref[:,0,:] @ qr_w^T + qr_b          (A rows stride L*D)
  gemm_kernel<0, 1, 1, 0><<<gG, bG, 0, stream>>>(
      ref, (size_t)LSEQ * D, 0, qr_w, qr_b, nullptr, nullptr, q0part);
  // p = q0 @ ktxt_w                          (A = sum of 8 q0 partials)
  gemm_kernel<1, 8, 0, 0><<<gG, bG, 0, stream>>>(
      q0part, D, P, ktxt_w, nullptr, nullptr, nullptr, ppart);
  // caption stream -> naccP, sAP (qdot computed in-kernel)
  cap_kernel<<<dim3(4, NB), bG, 0, stream>>>(cap, ppart, q0part, ktxt_b, naccP, sAP);
  // u = nacc @ ktxt_w^T + sA*ktxt_b          (A = sum of 4 nacc chunks)
  gemm_kernel<0, 4, 2, 0><<<gG, bG, 0, stream>>>(
      naccP, D, P, ktxt_w, ktxt_b, sAP, nullptr, upart);
  // w = u @ ktar_w                           (A = sum of 8 u partials)
  gemm_kernel<1, 8, 0, 0><<<gG, bG, 0, stream>>>(
      upart, D, P, ktar_w, nullptr, nullptr, nullptr, wpart);
  // target stream -> accP, ZP (cb computed in-kernel)
  tar_kernel<<<dim3(4, NB), bG, 0, stream>>>(tar, wpart, upart, ktar_b, accP, ZP);
  // out = softmax-merge(accP)/Z @ v_w^T + v_b  (A = sum of 4 chunks, row-scaled)
  gemm_kernel<0, 4, 1, 1><<<gG, bG, 0, stream>>>(
      accP, D, P, v_w, v_b, nullptr, ZP, outPart);
  // final reduction of 8 out partials
  reduce_out_kernel<<<128, bG, 0, stream>>>(outPart, out);
}